// Round 7
// baseline (522.056 us; speedup 1.0000x reference)
//
#include <hip/hip_runtime.h>
#include <hip/hip_bf16.h>
#include <hip/hip_cooperative_groups.h>

namespace cg = cooperative_groups;

typedef __bf16 bf16_t;
typedef bf16_t bf16x8 __attribute__((ext_vector_type(8)));
typedef bf16_t bf16x4 __attribute__((ext_vector_type(4)));
typedef float f32x4 __attribute__((ext_vector_type(4)));

typedef __attribute__((address_space(1))) const void gconst_void;
typedef __attribute__((address_space(3))) void lds_void;

__device__ __forceinline__ void async16(const bf16_t* g, bf16_t* l) {
  __builtin_amdgcn_global_load_lds((gconst_void*)g, (lds_void*)l, 16, 0, 0);
}

// ---- batched f32 -> bf16 conversion ----
struct CvtDesc { const float* src; bf16_t* dst; long n; };
struct CvtArgs { CvtDesc d[10]; };

__global__ __launch_bounds__(256) void cvt_many(CvtArgs a) {
  const CvtDesc de = a.d[blockIdx.y];
  long i = ((long)blockIdx.x * 256 + threadIdx.x) * 4;
  const long stride = (long)gridDim.x * 256 * 4;
  for (; i < de.n; i += stride) {
    float4 v = *(const float4*)(de.src + i);
    bf16x4 o;
    o[0] = (bf16_t)v.x; o[1] = (bf16_t)v.y; o[2] = (bf16_t)v.z; o[3] = (bf16_t)v.w;
    *(bf16x4*)(de.dst + i) = o;
  }
}

// ---- grouped GEMM: C[4096,N] = act(A[4096,K] @ W[N,K]^T + bias) ----
// Tile 128xBN (BN=64 or 128), 4 waves in 2x2, each wave owns 64x(BN/2).
// Depth-3 software pipeline: stage for step s issued at step s-2; raw
// s_barrier + counted vmcnt (never 0 in steady state). 3 LDS buffers.
// M fixed 4096 (32 row-tiles), N mult of BN, K mult of 32 (>=4 steps).
// act: 0=none 1=relu 2=sigmoid. Up to 2 independent problems per launch.
struct GDesc {
  const bf16_t* A; const bf16_t* W; const float* bias; void* C;
  int N, K, act;
};
struct GArgs { GDesc d[2]; int ntiles0; };

template <typename OutT, bool MINMAX, int BN>
__global__ __launch_bounds__(256) void gemm_gb(GArgs ga, float* __restrict__ pmin,
                                               float* __restrict__ pmax) {
  constexpr int NJ = BN / 32;        // B-frags per wave (wave owns BN/2 cols)
  const int b = blockIdx.x;
  const int p = (b >= ga.ntiles0) ? 1 : 0;
  const GDesc d = ga.d[p];
  const int local = b - (p ? ga.ntiles0 : 0);
  const int bm = (local & 31) * 128;   // 32 row tiles (M=4096)
  const int bn = (local >> 5) * BN;
  const int N = d.N, K = d.K;

  // triple-buffered LDS tiles: BN=64 -> 36 KB, BN=128 -> 48 KB
  __shared__ __align__(16) bf16_t As[3][128 * 32];
  __shared__ __align__(16) bf16_t Bs[3][BN * 32];

  const int t = threadIdx.x;
  const int wave = t >> 6;
  const int lane = t & 63;
  const int quad = lane >> 4;
  const int l15 = lane & 15;
  const int wm = (wave >> 1) * 64;        // waves 2M x 2N
  const int wn = (wave & 1) * (BN / 2);

  f32x4 acc[4][NJ];
#pragma unroll
  for (int i = 0; i < 4; ++i)
#pragma unroll
    for (int j = 0; j < NJ; ++j) acc[i][j] = (f32x4){0.f, 0.f, 0.f, 0.f};

  // Staging swizzle: LDS slot s of row r holds global k-chunk (s-r-(r>>2))&3;
  // reader (quad q) uses slot (q+r+(r>>2))&3 (2-way worst-case aliasing).
  const int c0 = t, c1 = t + 256;
  const int r0 = c0 >> 2, kc0 = ((c0 & 3) - r0 - (r0 >> 2)) & 3;
  const int r1 = c1 >> 2, kc1 = ((c1 & 3) - r1 - (r1 >> 2)) & 3;
  const bf16_t* pa0 = d.A + (long)(bm + r0) * K + kc0 * 8;
  const bf16_t* pa1 = d.A + (long)(bm + r1) * K + kc1 * 8;
  const bf16_t* pw0 = d.W + (long)(bn + r0) * K + kc0 * 8;
  const bf16_t* pw1 = d.W + (long)(bn + r1) * K + kc1 * 8;  // BN=128 only
  bf16_t* lA0 = &As[0][c0 * 8]; bf16_t* lA1 = &As[0][c1 * 8];
  bf16_t* lB0 = &Bs[0][c0 * 8]; bf16_t* lB1 = &Bs[0][c1 * 8];
  const int bufOffA = 128 * 32;
  const int bufOffB = BN * 32;

  auto stage = [&](int ke, int bi) {
    const int oA = bi * bufOffA, oB = bi * bufOffB;
    async16(pa0 + ke, lA0 + oA);
    async16(pa1 + ke, lA1 + oA);
    async16(pw0 + ke, lB0 + oB);
    if constexpr (BN == 128) async16(pw1 + ke, lB1 + oB);
  };

  auto compute = [&](int bi) {
    const bf16_t* as = As[bi];
    const bf16_t* bs = Bs[bi];
    bf16x8 af[4], bfr[NJ];
#pragma unroll
    for (int i = 0; i < 4; ++i) {
      const int r = wm + i * 16 + l15;
      af[i] = *(const bf16x8*)&as[r * 32 + ((quad + r + (r >> 2)) & 3) * 8];
    }
#pragma unroll
    for (int j = 0; j < NJ; ++j) {
      const int r = wn + j * 16 + l15;
      bfr[j] = *(const bf16x8*)&bs[r * 32 + ((quad + r + (r >> 2)) & 3) * 8];
    }
    // Swapped operand order: register quad holds 4 consecutive output cols.
#pragma unroll
    for (int i = 0; i < 4; ++i)
#pragma unroll
      for (int j = 0; j < NJ; ++j)
        acc[i][j] = __builtin_amdgcn_mfma_f32_16x16x32_bf16(bfr[j], af[i],
                                                            acc[i][j], 0, 0, 0);
  };

  const int nsteps = K >> 5;
  stage(0, 0);
  stage(32, 1);
  int s = 0;
  for (; s < nsteps - 2; ++s) {
    __builtin_amdgcn_s_barrier();
    __builtin_amdgcn_sched_barrier(0);
    stage((s + 2) * 32, (s + 2) % 3);
    if constexpr (BN == 128)
      asm volatile("s_waitcnt vmcnt(8)" ::: "memory");
    else
      asm volatile("s_waitcnt vmcnt(6)" ::: "memory");
    __builtin_amdgcn_s_barrier();
    __builtin_amdgcn_sched_barrier(0);
    compute(s % 3);
  }
  __builtin_amdgcn_s_barrier();
  if constexpr (BN == 128)
    asm volatile("s_waitcnt vmcnt(4)" ::: "memory");
  else
    asm volatile("s_waitcnt vmcnt(3)" ::: "memory");
  __builtin_amdgcn_s_barrier();
  __builtin_amdgcn_sched_barrier(0);
  compute(s % 3);
  ++s;
  asm volatile("s_waitcnt vmcnt(0)" ::: "memory");
  __builtin_amdgcn_s_barrier();
  __builtin_amdgcn_sched_barrier(0);
  compute(s % 3);

  // Swapped C/D layout: row = l15 (+i*16), col = quad*4 + reg (+j*16).
  OutT* C = (OutT*)d.C;
  const int row0 = bm + wm + l15;
  const int col0 = bn + wn + quad * 4;
  float mn = 3.4e38f, mx = -3.4e38f;
#pragma unroll
  for (int i = 0; i < 4; ++i) {
    const long row = row0 + i * 16;
#pragma unroll
    for (int j = 0; j < NJ; ++j) {
      const int col = col0 + j * 16;
      f32x4 bv = d.bias ? *(const f32x4*)&d.bias[col] : (f32x4){0.f, 0.f, 0.f, 0.f};
      f32x4 v;
#pragma unroll
      for (int r = 0; r < 4; ++r) {
        float x = acc[i][j][r] + bv[r];
        if (d.act == 1) x = fmaxf(x, 0.f);
        else if (d.act == 2) x = 1.f / (1.f + expf(-x));
        v[r] = x;
        if (MINMAX) { mn = fminf(mn, x); mx = fmaxf(mx, x); }
      }
      if constexpr (sizeof(OutT) == 4) {
        *(f32x4*)&((float*)C)[row * N + col] = v;
      } else {
        bf16x4 o;
        o[0] = (bf16_t)v[0]; o[1] = (bf16_t)v[1];
        o[2] = (bf16_t)v[2]; o[3] = (bf16_t)v[3];
        *(bf16x4*)&((bf16_t*)C)[row * N + col] = o;
      }
    }
  }
  if (MINMAX) {
#pragma unroll
    for (int off = 32; off > 0; off >>= 1) {
      mn = fminf(mn, __shfl_down(mn, off));
      mx = fmaxf(mx, __shfl_down(mx, off));
    }
    __shared__ float smn[4], smx[4];
    if (lane == 0) { smn[wave] = mn; smx[wave] = mx; }
    __syncthreads();
    if (t == 0) {
      pmin[blockIdx.x] = fminf(fminf(smn[0], smn[1]), fminf(smn[2], smn[3]));
      pmax[blockIdx.x] = fmaxf(fmaxf(smx[0], smx[1]), fmaxf(smx[2], smx[3]));
    }
  }
}

// ---- fused persistent scores + minmax + normalize (cooperative) ----
// C[4096,4096] = X1[4096,512] @ X2[4096,512]^T (f32), then in-place minmax
// normalize. Phase 1: grid-strided BN=64 GEMM tiles + per-block minmax
// partials. grid.sync. Phase 2: every block reduces all partials, then
// normalizes the tiles IT wrote (own-data re-read -> no cross-XCD hazard).
__global__ __launch_bounds__(256) void scores_fused(
    const bf16_t* __restrict__ X1, const bf16_t* __restrict__ X2,
    float* __restrict__ C, float* __restrict__ pmin, float* __restrict__ pmax) {
  constexpr int K = 512, N = 4096, NTILES = 2048;  // 32 row x 64 col tiles
  __shared__ __align__(16) bf16_t As[3][128 * 32];
  __shared__ __align__(16) bf16_t Bs[3][64 * 32];
  __shared__ float smn[4], smx[4];

  const int t = threadIdx.x;
  const int wave = t >> 6, lane = t & 63, quad = lane >> 4, l15 = lane & 15;
  const int wm = (wave >> 1) * 64, wn = (wave & 1) * 32;
  const int c0 = t, c1 = t + 256;
  const int r0 = c0 >> 2, kc0 = ((c0 & 3) - r0 - (r0 >> 2)) & 3;
  const int r1 = c1 >> 2, kc1 = ((c1 & 3) - r1 - (r1 >> 2)) & 3;
  const int bufOffA = 128 * 32, bufOffB = 64 * 32;

  float mn = 3.4e38f, mx = -3.4e38f;

  for (int idx = blockIdx.x; idx < NTILES; idx += gridDim.x) {
    const int bm = (idx & 31) * 128, bn = (idx >> 5) * 64;
    const bf16_t* pa0 = X1 + (long)(bm + r0) * K + kc0 * 8;
    const bf16_t* pa1 = X1 + (long)(bm + r1) * K + kc1 * 8;
    const bf16_t* pw0 = X2 + (long)(bn + r0) * K + kc0 * 8;
    bf16_t* lA0 = &As[0][c0 * 8]; bf16_t* lA1 = &As[0][c1 * 8];
    bf16_t* lB0 = &Bs[0][c0 * 8];

    f32x4 acc[4][2];
#pragma unroll
    for (int i = 0; i < 4; ++i)
#pragma unroll
      for (int j = 0; j < 2; ++j) acc[i][j] = (f32x4){0.f, 0.f, 0.f, 0.f};

    auto stage = [&](int ke, int bi) {
      const int oA = bi * bufOffA, oB = bi * bufOffB;
      async16(pa0 + ke, lA0 + oA);
      async16(pa1 + ke, lA1 + oA);
      async16(pw0 + ke, lB0 + oB);
    };
    auto compute = [&](int bi) {
      const bf16_t* as = As[bi];
      const bf16_t* bs = Bs[bi];
      bf16x8 af[4], bfr[2];
#pragma unroll
      for (int i = 0; i < 4; ++i) {
        const int r = wm + i * 16 + l15;
        af[i] = *(const bf16x8*)&as[r * 32 + ((quad + r + (r >> 2)) & 3) * 8];
      }
#pragma unroll
      for (int j = 0; j < 2; ++j) {
        const int r = wn + j * 16 + l15;
        bfr[j] = *(const bf16x8*)&bs[r * 32 + ((quad + r + (r >> 2)) & 3) * 8];
      }
#pragma unroll
      for (int i = 0; i < 4; ++i) {
        acc[i][0] = __builtin_amdgcn_mfma_f32_16x16x32_bf16(bfr[0], af[i],
                                                            acc[i][0], 0, 0, 0);
        acc[i][1] = __builtin_amdgcn_mfma_f32_16x16x32_bf16(bfr[1], af[i],
                                                            acc[i][1], 0, 0, 0);
      }
    };

    __syncthreads();  // prior tile fully consumed before re-staging buffers
    stage(0, 0);
    stage(32, 1);
    int s = 0;
    for (; s < 14; ++s) {   // 16 K-steps total (K=512)
      __builtin_amdgcn_s_barrier();
      __builtin_amdgcn_sched_barrier(0);
      stage((s + 2) * 32, (s + 2) % 3);
      asm volatile("s_waitcnt vmcnt(6)" ::: "memory");
      __builtin_amdgcn_s_barrier();
      __builtin_amdgcn_sched_barrier(0);
      compute(s % 3);
    }
    __builtin_amdgcn_s_barrier();
    asm volatile("s_waitcnt vmcnt(3)" ::: "memory");
    __builtin_amdgcn_s_barrier();
    __builtin_amdgcn_sched_barrier(0);
    compute(14 % 3);
    asm volatile("s_waitcnt vmcnt(0)" ::: "memory");
    __builtin_amdgcn_s_barrier();
    __builtin_amdgcn_sched_barrier(0);
    compute(15 % 3);

    const int row0 = bm + wm + l15;
    const int col0 = bn + wn + quad * 4;
#pragma unroll
    for (int i = 0; i < 4; ++i) {
      const long row = row0 + i * 16;
#pragma unroll
      for (int j = 0; j < 2; ++j) {
        const int col = col0 + j * 16;
        f32x4 v;
#pragma unroll
        for (int r = 0; r < 4; ++r) {
          float x = acc[i][j][r];
          v[r] = x;
          mn = fminf(mn, x); mx = fmaxf(mx, x);
        }
        *(f32x4*)&C[row * N + col] = v;
      }
    }
  }

  // per-block partial minmax
#pragma unroll
  for (int off = 32; off > 0; off >>= 1) {
    mn = fminf(mn, __shfl_down(mn, off));
    mx = fmaxf(mx, __shfl_down(mx, off));
  }
  if (lane == 0) { smn[wave] = mn; smx[wave] = mx; }
  __syncthreads();
  if (t == 0) {
    pmin[blockIdx.x] = fminf(fminf(smn[0], smn[1]), fminf(smn[2], smn[3]));
    pmax[blockIdx.x] = fmaxf(fmaxf(smx[0], smx[1]), fmaxf(smx[2], smx[3]));
  }
  __threadfence();
  cg::this_grid().sync();

  // every block computes the global minmax from all partials
  float gmn = 3.4e38f, gmx = -3.4e38f;
  for (int i = t; i < (int)gridDim.x; i += 256) {
    gmn = fminf(gmn, pmin[i]);
    gmx = fmaxf(gmx, pmax[i]);
  }
#pragma unroll
  for (int off = 32; off > 0; off >>= 1) {
    gmn = fminf(gmn, __shfl_down(gmn, off));
    gmx = fmaxf(gmx, __shfl_down(gmx, off));
  }
  __syncthreads();  // smn/smx reuse
  if (lane == 0) { smn[wave] = gmn; smx[wave] = gmx; }
  __syncthreads();
  gmn = fminf(fminf(smn[0], smn[1]), fminf(smn[2], smn[3]));
  gmx = fmaxf(fmaxf(smx[0], smx[1]), fmaxf(smx[2], smx[3]));
  const float inv = 1.f / (gmx - gmn);

  // normalize own tiles in place (L3-warm, same-block data)
  for (int idx = blockIdx.x; idx < NTILES; idx += gridDim.x) {
    const int bm = (idx & 31) * 128, bn = (idx >> 5) * 64;
    const int rr = t >> 4, cc = (t & 15) * 4;
    for (int r = rr; r < 128; r += 16) {
      float4* p = (float4*)&C[(long)(bm + r) * N + bn + cc];
      float4 v = *p;
      v.x = (v.x - gmn) * inv;
      v.y = (v.y - gmn) * inv;
      v.z = (v.z - gmn) * inv;
      v.w = (v.w - gmn) * inv;
      *p = v;
    }
  }
}

// ---- merged projection dots: out[row] = sigmoid(dot(A[row], w) + b) ----
struct RDesc { const bf16_t* A; const float* w; const float* b; float* out; int K; };

__global__ __launch_bounds__(64) void rowdot2(RDesc d0, RDesc d1) {
  const RDesc d = blockIdx.y ? d1 : d0;
  const int row = blockIdx.x;
  const int lane = threadIdx.x;
  const bf16_t* a = d.A + (long)row * d.K;
  float s = 0.f;
  for (int k = lane * 8; k < d.K; k += 64 * 8) {
    bf16x8 av = *(const bf16x8*)&a[k];
    float4 w0 = *(const float4*)&d.w[k];
    float4 w1 = *(const float4*)&d.w[k + 4];
    s += (float)av[0] * w0.x + (float)av[1] * w0.y +
         (float)av[2] * w0.z + (float)av[3] * w0.w +
         (float)av[4] * w1.x + (float)av[5] * w1.y +
         (float)av[6] * w1.z + (float)av[7] * w1.w;
  }
#pragma unroll
  for (int off = 32; off > 0; off >>= 1) s += __shfl_down(s, off);
  if (lane == 0) d.out[row] = 1.f / (1.f + expf(-(s + d.b[0])));
}

extern "C" void kernel_launch(void* const* d_in, const int* in_sizes, int n_in,
                              void* d_out, int out_size, void* d_ws,
                              size_t ws_size, hipStream_t stream) {
  const float* x1   = (const float*)d_in[0];
  const float* x2   = (const float*)d_in[1];
  const float* W1_1 = (const float*)d_in[2];   const float* b1_1 = (const float*)d_in[3];
  const float* W1_2 = (const float*)d_in[4];   const float* b1_2 = (const float*)d_in[5];
  const float* W1_3 = (const float*)d_in[6];   const float* b1_3 = (const float*)d_in[7];
  const float* W1_4 = (const float*)d_in[8];   const float* b1_4 = (const float*)d_in[9];
  const float* W1_5 = (const float*)d_in[10];  const float* b1_5 = (const float*)d_in[11];
  const float* Wp1  = (const float*)d_in[12];  const float* bp1  = (const float*)d_in[13];
  const float* W2_1 = (const float*)d_in[14];  const float* b2_1 = (const float*)d_in[15];
  const float* W2_2 = (const float*)d_in[16];  const float* b2_2 = (const float*)d_in[17];
  const float* W2_3 = (const float*)d_in[18];  const float* b2_3 = (const float*)d_in[19];
  const float* Wp2  = (const float*)d_in[20];  const float* bp2  = (const float*)d_in[21];

  float* out = (float*)d_out;
  float* out_pre_data  = out;
  float* out_pre_dm    = out + 4096;                      // 64 MB f32
  float* out_pre_model = out + 4096 + (long)4096 * 4096;

  // 64 MB arena inside the (dead until scores) pre_dm output region.
  char* arena = (char*)out_pre_dm;
  const size_t MB = 1024 * 1024;
  bf16_t* x1b   = (bf16_t*)(arena);            // 8 MB  [4096,1024]
  bf16_t* x2b   = (bf16_t*)(arena + 8 * MB);   // 4 MB  [4096,512]
  bf16_t* W1_1b = (bf16_t*)(arena + 12 * MB);  // 4 MB
  bf16_t* W1_2b = (bf16_t*)(arena + 16 * MB);  // 4 MB
  bf16_t* W1_3b = (bf16_t*)(arena + 20 * MB);  // 1 MB
  bf16_t* W1_4b = (bf16_t*)(arena + 21 * MB);  // 1 MB
  bf16_t* W1_5b = (bf16_t*)(arena + 22 * MB);  // 4 MB
  bf16_t* W2_1b = (bf16_t*)(arena + 26 * MB);  // 1 MB
  bf16_t* W2_2b = (bf16_t*)(arena + 27 * MB);  // 1 MB
  bf16_t* W2_3b = (bf16_t*)(arena + 28 * MB);  // 1 MB
  bf16_t* bufA  = (bf16_t*)(arena + 32 * MB);  // 16 MB [4096,2048] B1 even
  bf16_t* bufB  = (bf16_t*)(arena + 48 * MB);  // 8 MB  [4096,1024] B1 odd
  bf16_t* bufC  = (bf16_t*)(arena + 56 * MB);  // 8 MB  [4096,1024] B2

  char* ws = (char*)d_ws;
  bf16_t* bufX1 = (bf16_t*)(ws);            // 4 MB [4096,512]
  bf16_t* bufX2 = (bf16_t*)(ws + 4 * MB);   // 4 MB [4096,512]
  float* pmin = (float*)(ws + 8 * MB);
  float* pmax = pmin + 2048;

  CvtArgs ca;
  ca.d[0] = {x1,   x1b,   (long)4096 * 1024};
  ca.d[1] = {x2,   x2b,   (long)4096 * 512};
  ca.d[2] = {W1_1, W1_1b, (long)2048 * 1024};
  ca.d[3] = {W1_2, W1_2b, (long)1024 * 2048};
  ca.d[4] = {W1_3, W1_3b, (long)512 * 1024};
  ca.d[5] = {W1_4, W1_4b, (long)1024 * 512};
  ca.d[6] = {W1_5, W1_5b, (long)2048 * 1024};
  ca.d[7] = {W2_1, W2_1b, (long)1024 * 512};
  ca.d[8] = {W2_2, W2_2b, (long)512 * 1024};
  ca.d[9] = {W2_3, W2_3b, (long)1024 * 512};
  cvt_many<<<dim3(192, 10), 256, 0, stream>>>(ca);

  GArgs g;

  // G1: B1L1 (relu) + B2L1 (relu) at BN=128 (tiles = 32 * N/128)
  g.d[0] = {x1b, W1_1b, b1_1, bufA, 2048, 1024, 1};
  g.d[1] = {x2b, W2_1b, b2_1, bufC, 1024, 512, 1};
  g.ntiles0 = 512;
  gemm_gb<bf16_t, false, 128><<<768, 256, 0, stream>>>(g, nullptr, nullptr);

  // G2: B1L2 (relu, 512) + B2L2 (sigmoid, 256) at BN=64 (tiles = 32 * N/64)
  g.d[0] = {bufA, W1_2b, b1_2, bufB, 1024, 2048, 1};
  g.d[1] = {bufC, W2_2b, b2_2, bufX2, 512, 1024, 2};
  g.ntiles0 = 512;
  gemm_gb<bf16_t, false, 64><<<768, 256, 0, stream>>>(g, nullptr, nullptr);

  // G3: B1L3 (sigmoid, 256) + B2L3 (relu, 512) at BN=64
  g.d[0] = {bufB, W1_3b, b1_3, bufX1, 512, 1024, 2};
  g.d[1] = {bufX2, W2_3b, b2_3, bufC, 1024, 512, 1};
  g.ntiles0 = 256;
  gemm_gb<bf16_t, false, 64><<<768, 256, 0, stream>>>(g, nullptr, nullptr);

  // B1L4 (relu, 512) at BN=64
  g.d[0] = {bufX1, W1_4b, b1_4, bufB, 1024, 512, 1};
  g.d[1] = g.d[0];
  g.ntiles0 = 512;
  gemm_gb<bf16_t, false, 64><<<512, 256, 0, stream>>>(g, nullptr, nullptr);

  // B1L5 (relu, 1024) at BN=64
  g.d[0] = {bufB, W1_5b, b1_5, bufA, 2048, 1024, 1};
  g.d[1] = g.d[0];
  g.ntiles0 = 1024;
  gemm_gb<bf16_t, false, 64><<<1024, 256, 0, stream>>>(g, nullptr, nullptr);

  // both projections
  RDesc r0 = {bufA, Wp1, bp1, out_pre_data, 2048};
  RDesc r1 = {bufC, Wp2, bp2, out_pre_model, 1024};
  rowdot2<<<dim3(4096, 2), 64, 0, stream>>>(r0, r1);

  // fused persistent scores + minmax + normalize (cooperative launch).
  // Grid sized to guaranteed co-residency; tiles grid-strided inside.
  int nb = 0;
  hipOccupancyMaxActiveBlocksPerMultiprocessor(&nb, scores_fused, 256, 0);
  if (nb < 1) nb = 1;
  int sg = nb * 256;
  if (sg > 2048) sg = 2048;
  const bf16_t* sX1 = bufX1;
  const bf16_t* sX2 = bufX2;
  float* sC = out_pre_dm;
  void* kargs[] = {(void*)&sX1, (void*)&sX2, (void*)&sC, (void*)&pmin, (void*)&pmax};
  hipLaunchCooperativeKernel(scores_fused, dim3(sg), dim3(256), kargs, 0, stream);
}

// Round 8
// 348.992 us; speedup vs baseline: 1.4959x; 1.4959x over previous
//
#include <hip/hip_runtime.h>
#include <hip/hip_bf16.h>

typedef __bf16 bf16_t;
typedef bf16_t bf16x8 __attribute__((ext_vector_type(8)));
typedef bf16_t bf16x4 __attribute__((ext_vector_type(4)));
typedef float f32x4 __attribute__((ext_vector_type(4)));

typedef __attribute__((address_space(1))) const void gconst_void;
typedef __attribute__((address_space(3))) void lds_void;

__device__ __forceinline__ void async16(const bf16_t* g, bf16_t* l) {
  __builtin_amdgcn_global_load_lds((gconst_void*)g, (lds_void*)l, 16, 0, 0);
}

// ---- batched f32 -> bf16 conversion ----
struct CvtDesc { const float* src; bf16_t* dst; long n; };
struct CvtArgs { CvtDesc d[10]; };

__global__ __launch_bounds__(256) void cvt_many(CvtArgs a) {
  const CvtDesc de = a.d[blockIdx.y];
  long i = ((long)blockIdx.x * 256 + threadIdx.x) * 4;
  const long stride = (long)gridDim.x * 256 * 4;
  for (; i < de.n; i += stride) {
    float4 v = *(const float4*)(de.src + i);
    bf16x4 o;
    o[0] = (bf16_t)v.x; o[1] = (bf16_t)v.y; o[2] = (bf16_t)v.z; o[3] = (bf16_t)v.w;
    *(bf16x4*)(de.dst + i) = o;
  }
}

// ---- grouped GEMM: C[4096,N] = act(A[4096,K] @ W[N,K]^T + bias) ----
// Tile 128xBN (BN=64 or 128), 4 waves in 2x2, each wave owns 64x(BN/2).
// Depth-3 software pipeline: stage for step s issued at step s-2; raw
// s_barrier + counted vmcnt (never 0 in steady state). 3 LDS buffers.
// M fixed 4096 (32 row-tiles), N mult of BN, K mult of 32 (>=4 steps).
// act: 0=none 1=relu 2=sigmoid. Up to 2 independent problems per launch.
struct GDesc {
  const bf16_t* A; const bf16_t* W; const float* bias; void* C;
  int N, K, act;
};
struct GArgs { GDesc d[2]; int ntiles0; };

template <typename OutT, bool MINMAX, int BN>
__global__ __launch_bounds__(256) void gemm_gb(GArgs ga, float* __restrict__ pmin,
                                               float* __restrict__ pmax) {
  constexpr int NJ = BN / 32;        // B-frags per wave (wave owns BN/2 cols)
  const int b = blockIdx.x;
  const int p = (b >= ga.ntiles0) ? 1 : 0;
  const GDesc d = ga.d[p];
  const int local = b - (p ? ga.ntiles0 : 0);
  const int bm = (local & 31) * 128;   // 32 row tiles (M=4096)
  const int bn = (local >> 5) * BN;
  const int N = d.N, K = d.K;

  // triple-buffered LDS tiles: BN=64 -> 36 KB, BN=128 -> 48 KB
  __shared__ __align__(16) bf16_t As[3][128 * 32];
  __shared__ __align__(16) bf16_t Bs[3][BN * 32];

  const int t = threadIdx.x;
  const int wave = t >> 6;
  const int lane = t & 63;
  const int quad = lane >> 4;
  const int l15 = lane & 15;
  const int wm = (wave >> 1) * 64;        // waves 2M x 2N
  const int wn = (wave & 1) * (BN / 2);

  f32x4 acc[4][NJ];
#pragma unroll
  for (int i = 0; i < 4; ++i)
#pragma unroll
    for (int j = 0; j < NJ; ++j) acc[i][j] = (f32x4){0.f, 0.f, 0.f, 0.f};

  // Staging swizzle: LDS slot s of row r holds global k-chunk (s-r-(r>>2))&3;
  // reader (quad q) uses slot (q+r+(r>>2))&3 (2-way worst-case aliasing).
  const int c0 = t, c1 = t + 256;
  const int r0 = c0 >> 2, kc0 = ((c0 & 3) - r0 - (r0 >> 2)) & 3;
  const int r1 = c1 >> 2, kc1 = ((c1 & 3) - r1 - (r1 >> 2)) & 3;
  const bf16_t* pa0 = d.A + (long)(bm + r0) * K + kc0 * 8;
  const bf16_t* pa1 = d.A + (long)(bm + r1) * K + kc1 * 8;
  const bf16_t* pw0 = d.W + (long)(bn + r0) * K + kc0 * 8;
  const bf16_t* pw1 = d.W + (long)(bn + r1) * K + kc1 * 8;  // BN=128 only
  bf16_t* lA0 = &As[0][c0 * 8]; bf16_t* lA1 = &As[0][c1 * 8];
  bf16_t* lB0 = &Bs[0][c0 * 8]; bf16_t* lB1 = &Bs[0][c1 * 8];
  const int bufOffA = 128 * 32;
  const int bufOffB = BN * 32;

  auto stage = [&](int ke, int bi) {
    const int oA = bi * bufOffA, oB = bi * bufOffB;
    async16(pa0 + ke, lA0 + oA);
    async16(pa1 + ke, lA1 + oA);
    async16(pw0 + ke, lB0 + oB);
    if constexpr (BN == 128) async16(pw1 + ke, lB1 + oB);
  };

  auto compute = [&](int bi) {
    const bf16_t* as = As[bi];
    const bf16_t* bs = Bs[bi];
    bf16x8 af[4], bfr[NJ];
#pragma unroll
    for (int i = 0; i < 4; ++i) {
      const int r = wm + i * 16 + l15;
      af[i] = *(const bf16x8*)&as[r * 32 + ((quad + r + (r >> 2)) & 3) * 8];
    }
#pragma unroll
    for (int j = 0; j < NJ; ++j) {
      const int r = wn + j * 16 + l15;
      bfr[j] = *(const bf16x8*)&bs[r * 32 + ((quad + r + (r >> 2)) & 3) * 8];
    }
    // Swapped operand order: register quad holds 4 consecutive output cols.
#pragma unroll
    for (int i = 0; i < 4; ++i)
#pragma unroll
      for (int j = 0; j < NJ; ++j)
        acc[i][j] = __builtin_amdgcn_mfma_f32_16x16x32_bf16(bfr[j], af[i],
                                                            acc[i][j], 0, 0, 0);
  };

  const int nsteps = K >> 5;
  stage(0, 0);
  stage(32, 1);
  int s = 0;
  for (; s < nsteps - 2; ++s) {
    __builtin_amdgcn_s_barrier();
    __builtin_amdgcn_sched_barrier(0);
    stage((s + 2) * 32, (s + 2) % 3);
    if constexpr (BN == 128)
      asm volatile("s_waitcnt vmcnt(8)" ::: "memory");
    else
      asm volatile("s_waitcnt vmcnt(6)" ::: "memory");
    __builtin_amdgcn_s_barrier();
    __builtin_amdgcn_sched_barrier(0);
    compute(s % 3);
  }
  __builtin_amdgcn_s_barrier();
  if constexpr (BN == 128)
    asm volatile("s_waitcnt vmcnt(4)" ::: "memory");
  else
    asm volatile("s_waitcnt vmcnt(3)" ::: "memory");
  __builtin_amdgcn_s_barrier();
  __builtin_amdgcn_sched_barrier(0);
  compute(s % 3);
  ++s;
  asm volatile("s_waitcnt vmcnt(0)" ::: "memory");
  __builtin_amdgcn_s_barrier();
  __builtin_amdgcn_sched_barrier(0);
  compute(s % 3);

  // Swapped C/D layout: row = l15 (+i*16), col = quad*4 + reg (+j*16).
  OutT* C = (OutT*)d.C;
  const int row0 = bm + wm + l15;
  const int col0 = bn + wn + quad * 4;
  float mn = 3.4e38f, mx = -3.4e38f;
#pragma unroll
  for (int i = 0; i < 4; ++i) {
    const long row = row0 + i * 16;
#pragma unroll
    for (int j = 0; j < NJ; ++j) {
      const int col = col0 + j * 16;
      f32x4 bv = d.bias ? *(const f32x4*)&d.bias[col] : (f32x4){0.f, 0.f, 0.f, 0.f};
      f32x4 v;
#pragma unroll
      for (int r = 0; r < 4; ++r) {
        float x = acc[i][j][r] + bv[r];
        if (d.act == 1) x = fmaxf(x, 0.f);
        else if (d.act == 2) x = 1.f / (1.f + expf(-x));
        v[r] = x;
        if (MINMAX) { mn = fminf(mn, x); mx = fmaxf(mx, x); }
      }
      if constexpr (sizeof(OutT) == 4) {
        *(f32x4*)&((float*)C)[row * N + col] = v;
      } else {
        bf16x4 o;
        o[0] = (bf16_t)v[0]; o[1] = (bf16_t)v[1];
        o[2] = (bf16_t)v[2]; o[3] = (bf16_t)v[3];
        *(bf16x4*)&((bf16_t*)C)[row * N + col] = o;
      }
    }
  }
  if (MINMAX) {
#pragma unroll
    for (int off = 32; off > 0; off >>= 1) {
      mn = fminf(mn, __shfl_down(mn, off));
      mx = fmaxf(mx, __shfl_down(mx, off));
    }
    __shared__ float smn[4], smx[4];
    if (lane == 0) { smn[wave] = mn; smx[wave] = mx; }
    __syncthreads();
    if (t == 0) {
      pmin[blockIdx.x] = fminf(fminf(smn[0], smn[1]), fminf(smn[2], smn[3]));
      pmax[blockIdx.x] = fmaxf(fmaxf(smx[0], smx[1]), fmaxf(smx[2], smx[3]));
    }
  }
}

// ---- merged projection dots: out[row] = sigmoid(dot(A[row], w) + b) ----
struct RDesc { const bf16_t* A; const float* w; const float* b; float* out; int K; };

__global__ __launch_bounds__(64) void rowdot2(RDesc d0, RDesc d1) {
  const RDesc d = blockIdx.y ? d1 : d0;
  const int row = blockIdx.x;
  const int lane = threadIdx.x;
  const bf16_t* a = d.A + (long)row * d.K;
  float s = 0.f;
  for (int k = lane * 8; k < d.K; k += 64 * 8) {
    bf16x8 av = *(const bf16x8*)&a[k];
    float4 w0 = *(const float4*)&d.w[k];
    float4 w1 = *(const float4*)&d.w[k + 4];
    s += (float)av[0] * w0.x + (float)av[1] * w0.y +
         (float)av[2] * w0.z + (float)av[3] * w0.w +
         (float)av[4] * w1.x + (float)av[5] * w1.y +
         (float)av[6] * w1.z + (float)av[7] * w1.w;
  }
#pragma unroll
  for (int off = 32; off > 0; off >>= 1) s += __shfl_down(s, off);
  if (lane == 0) d.out[row] = 1.f / (1.f + expf(-(s + d.b[0])));
}

// ---- normalize with folded final minmax reduce ----
// Every block reduces the nb-entry partial arrays (L2-resident broadcast,
// ~16 KB) then normalizes its grid-stride slice in place.
__global__ __launch_bounds__(256) void normalize_k(
    float* __restrict__ out, const float* __restrict__ pmin,
    const float* __restrict__ pmax, int nb, long n) {
  float mn = 3.4e38f, mx = -3.4e38f;
  for (int i = threadIdx.x; i < nb; i += 256) {
    mn = fminf(mn, pmin[i]);
    mx = fmaxf(mx, pmax[i]);
  }
#pragma unroll
  for (int off = 32; off > 0; off >>= 1) {
    mn = fminf(mn, __shfl_down(mn, off));
    mx = fmaxf(mx, __shfl_down(mx, off));
  }
  __shared__ float smn[4], smx[4];
  const int wv = threadIdx.x >> 6, ln = threadIdx.x & 63;
  if (ln == 0) { smn[wv] = mn; smx[wv] = mx; }
  __syncthreads();
  mn = fminf(fminf(smn[0], smn[1]), fminf(smn[2], smn[3]));
  mx = fmaxf(fmaxf(smx[0], smx[1]), fmaxf(smx[2], smx[3]));
  const float inv = 1.f / (mx - mn);

  long i = ((long)blockIdx.x * 256 + threadIdx.x) * 4;
  const long stride = (long)gridDim.x * 256 * 4;
  for (; i < n; i += stride) {
    float4 v = *(const float4*)&out[i];
    v.x = (v.x - mn) * inv;
    v.y = (v.y - mn) * inv;
    v.z = (v.z - mn) * inv;
    v.w = (v.w - mn) * inv;
    *(float4*)&out[i] = v;
  }
}

extern "C" void kernel_launch(void* const* d_in, const int* in_sizes, int n_in,
                              void* d_out, int out_size, void* d_ws,
                              size_t ws_size, hipStream_t stream) {
  const float* x1   = (const float*)d_in[0];
  const float* x2   = (const float*)d_in[1];
  const float* W1_1 = (const float*)d_in[2];   const float* b1_1 = (const float*)d_in[3];
  const float* W1_2 = (const float*)d_in[4];   const float* b1_2 = (const float*)d_in[5];
  const float* W1_3 = (const float*)d_in[6];   const float* b1_3 = (const float*)d_in[7];
  const float* W1_4 = (const float*)d_in[8];   const float* b1_4 = (const float*)d_in[9];
  const float* W1_5 = (const float*)d_in[10];  const float* b1_5 = (const float*)d_in[11];
  const float* Wp1  = (const float*)d_in[12];  const float* bp1  = (const float*)d_in[13];
  const float* W2_1 = (const float*)d_in[14];  const float* b2_1 = (const float*)d_in[15];
  const float* W2_2 = (const float*)d_in[16];  const float* b2_2 = (const float*)d_in[17];
  const float* W2_3 = (const float*)d_in[18];  const float* b2_3 = (const float*)d_in[19];
  const float* Wp2  = (const float*)d_in[20];  const float* bp2  = (const float*)d_in[21];

  float* out = (float*)d_out;
  float* out_pre_data  = out;
  float* out_pre_dm    = out + 4096;                      // 64 MB f32
  float* out_pre_model = out + 4096 + (long)4096 * 4096;

  // 64 MB arena inside the (dead until scores) pre_dm output region.
  char* arena = (char*)out_pre_dm;
  const size_t MB = 1024 * 1024;
  bf16_t* x1b   = (bf16_t*)(arena);            // 8 MB  [4096,1024]
  bf16_t* x2b   = (bf16_t*)(arena + 8 * MB);   // 4 MB  [4096,512]
  bf16_t* W1_1b = (bf16_t*)(arena + 12 * MB);  // 4 MB
  bf16_t* W1_2b = (bf16_t*)(arena + 16 * MB);  // 4 MB
  bf16_t* W1_3b = (bf16_t*)(arena + 20 * MB);  // 1 MB
  bf16_t* W1_4b = (bf16_t*)(arena + 21 * MB);  // 1 MB
  bf16_t* W1_5b = (bf16_t*)(arena + 22 * MB);  // 4 MB
  bf16_t* W2_1b = (bf16_t*)(arena + 26 * MB);  // 1 MB
  bf16_t* W2_2b = (bf16_t*)(arena + 27 * MB);  // 1 MB
  bf16_t* W2_3b = (bf16_t*)(arena + 28 * MB);  // 1 MB
  bf16_t* bufA  = (bf16_t*)(arena + 32 * MB);  // 16 MB [4096,2048] B1 even
  bf16_t* bufB  = (bf16_t*)(arena + 48 * MB);  // 8 MB  [4096,1024] B1 odd
  bf16_t* bufC  = (bf16_t*)(arena + 56 * MB);  // 8 MB  [4096,1024] B2

  char* ws = (char*)d_ws;
  bf16_t* bufX1 = (bf16_t*)(ws);            // 4 MB [4096,512]
  bf16_t* bufX2 = (bf16_t*)(ws + 4 * MB);   // 4 MB [4096,512]
  float* pmin = (float*)(ws + 8 * MB);
  float* pmax = pmin + 2048;

  CvtArgs ca;
  ca.d[0] = {x1,   x1b,   (long)4096 * 1024};
  ca.d[1] = {x2,   x2b,   (long)4096 * 512};
  ca.d[2] = {W1_1, W1_1b, (long)2048 * 1024};
  ca.d[3] = {W1_2, W1_2b, (long)1024 * 2048};
  ca.d[4] = {W1_3, W1_3b, (long)512 * 1024};
  ca.d[5] = {W1_4, W1_4b, (long)1024 * 512};
  ca.d[6] = {W1_5, W1_5b, (long)2048 * 1024};
  ca.d[7] = {W2_1, W2_1b, (long)1024 * 512};
  ca.d[8] = {W2_2, W2_2b, (long)512 * 1024};
  ca.d[9] = {W2_3, W2_3b, (long)1024 * 512};
  cvt_many<<<dim3(192, 10), 256, 0, stream>>>(ca);

  const long nS = (long)4096 * 4096;
  GArgs g;

  // G1: B1L1 (relu) + B2L1 (relu) at BN=128 (tiles = 32 * N/128)
  g.d[0] = {x1b, W1_1b, b1_1, bufA, 2048, 1024, 1};
  g.d[1] = {x2b, W2_1b, b2_1, bufC, 1024, 512, 1};
  g.ntiles0 = 512;
  gemm_gb<bf16_t, false, 128><<<768, 256, 0, stream>>>(g, nullptr, nullptr);

  // G2: B1L2 (relu, 512) + B2L2 (sigmoid, 256) at BN=64 (tiles = 32 * N/64)
  g.d[0] = {bufA, W1_2b, b1_2, bufB, 1024, 2048, 1};
  g.d[1] = {bufC, W2_2b, b2_2, bufX2, 512, 1024, 2};
  g.ntiles0 = 512;
  gemm_gb<bf16_t, false, 64><<<768, 256, 0, stream>>>(g, nullptr, nullptr);

  // G3: B1L3 (sigmoid, 256) + B2L3 (relu, 512) at BN=64
  g.d[0] = {bufB, W1_3b, b1_3, bufX1, 512, 1024, 2};
  g.d[1] = {bufX2, W2_3b, b2_3, bufC, 1024, 512, 1};
  g.ntiles0 = 256;
  gemm_gb<bf16_t, false, 64><<<768, 256, 0, stream>>>(g, nullptr, nullptr);

  // B1L4 (relu, 512) at BN=64
  g.d[0] = {bufX1, W1_4b, b1_4, bufB, 1024, 512, 1};
  g.d[1] = g.d[0];
  g.ntiles0 = 512;
  gemm_gb<bf16_t, false, 64><<<512, 256, 0, stream>>>(g, nullptr, nullptr);

  // B1L5 (relu, 1024) at BN=64
  g.d[0] = {bufB, W1_5b, b1_5, bufA, 2048, 1024, 1};
  g.d[1] = g.d[0];
  g.ntiles0 = 1024;
  gemm_gb<bf16_t, false, 64><<<1024, 256, 0, stream>>>(g, nullptr, nullptr);

  // both projections
  RDesc r0 = {bufA, Wp1, bp1, out_pre_data, 2048};
  RDesc r1 = {bufC, Wp2, bp2, out_pre_model, 1024};
  rowdot2<<<dim3(4096, 2), 64, 0, stream>>>(r0, r1);

  // scores (f32, fused per-block min/max partials) at BN=64, grid 2048
  g.d[0] = {bufX1, bufX2, nullptr, out_pre_dm, 4096, 512, 0};
  g.d[1] = g.d[0];
  g.ntiles0 = 2048;
  gemm_gb<float, true, 64><<<2048, 256, 0, stream>>>(g, pmin, pmax);

  // normalize with folded partial-minmax reduce (one fewer dispatch)
  normalize_k<<<2048, 256, 0, stream>>>(out_pre_dm, pmin, pmax, 2048, nS);
}